// Round 1
// baseline (470.588 us; speedup 1.0000x reference)
//
#include <hip/hip_runtime.h>

#define T_SEQ 2048
#define D_MODEL 1024
#define NHEADS 16
#define HSZ 64
#define BATCH 4

typedef __bf16 bf16x8 __attribute__((ext_vector_type(8)));
typedef float f32x4 __attribute__((ext_vector_type(4)));

__device__ __forceinline__ unsigned short f2bf(float f) {
    unsigned int u = __builtin_bit_cast(unsigned int, f);
    u += 0x7fff + ((u >> 16) & 1);   // RNE
    return (unsigned short)(u >> 16);
}

__device__ __forceinline__ void gld_lds16(const void* g, void* lds) {
    __builtin_amdgcn_global_load_lds(
        (const __attribute__((address_space(1))) unsigned int*)g,
        (__attribute__((address_space(3))) unsigned int*)lds, 16, 0, 0);
}

__device__ __forceinline__ bf16x8 ld8(const unsigned short* p) {
    return *(const bf16x8*)p;
}

// ---------------- casts ----------------
__global__ void cast_x(const float* __restrict__ src, unsigned short* __restrict__ dst, int n4) {
    int i = blockIdx.x * blockDim.x + threadIdx.x;
    if (i >= n4) return;
    float4 v = ((const float4*)src)[i];
    ushort4 o;
    o.x = f2bf(v.x); o.y = f2bf(v.y); o.z = f2bf(v.z); o.w = f2bf(v.w);
    ((ushort4*)dst)[i] = o;
}

__global__ void cast_w(const float* __restrict__ w0, const float* __restrict__ w1,
                       const float* __restrict__ w2, const float* __restrict__ w3,
                       unsigned short* __restrict__ dst) {
    const float* srcs[4] = {w0, w1, w2, w3};
    int wsel = blockIdx.y;
    const float4* src = (const float4*)srcs[wsel];
    int i = blockIdx.x * blockDim.x + threadIdx.x;   // 0..262143
    float4 v = src[i];
    ushort4 o;
    o.x = f2bf(v.x); o.y = f2bf(v.y); o.z = f2bf(v.z); o.w = f2bf(v.w);
    ((ushort4*)(dst + (size_t)wsel * 1048576))[i] = o;
}

// ---------------- T5 bias table: bias_tab[h][delta+2047], pre-multiplied by log2(e) ----
__global__ void bias_table(const float* __restrict__ rel_emb, float* __restrict__ bias_tab) {
    int idx = blockIdx.x * blockDim.x + threadIdx.x;
    if (idx >= NHEADS * 4095) return;
    int h = idx / 4095;
    int rp = (idx % 4095) - 2047;           // delta = mem - ctx
    int bucket = rp > 0 ? 16 : 0;
    int arp = rp < 0 ? -rp : rp;
    if (arp < 8) {
        bucket += arp;
    } else {
        float f = logf((float)arp / 7.0f) * (8.0f / logf(128.0f / 7.0f));
        int rl = 7 + (int)f;                // trunc == floor (f>0)
        bucket += rl < 15 ? rl : 15;
    }
    bias_tab[idx] = rel_emb[bucket * NHEADS + h] * 1.4426950408889634f;
}

// ---------------- GEMM: C[M,N] = A[M,K] * B[N,K]^T  (bf16 in, fp32 acc) -------------
// MODE 0: Q head-split bf16, scaled by 0.125*log2(e)
// MODE 1: K head-split bf16
// MODE 2: V transposed per head [B,NH,HS,T] bf16
// MODE 3: plain fp32 [M,N]
template<int MODE>
__global__ __launch_bounds__(256, 2) void gemm_bt(
    const unsigned short* __restrict__ A,
    const unsigned short* __restrict__ Bw,
    void* __restrict__ out)
{
    constexpr int K = 1024;
    __shared__ unsigned short As[128 * 64];
    __shared__ unsigned short Bs[128 * 64];

    const int tid  = threadIdx.x;
    const int wave = tid >> 6;
    const int lane = tid & 63;
    const int quad = lane >> 4;
    const int l16  = lane & 15;
    const int wm   = wave >> 1;
    const int wn   = wave & 1;
    const int bn   = blockIdx.x;
    const int bm   = blockIdx.y;

    // staging map: 16 wave-calls (4/wave) of 8 rows x 8 swizzled 16B chunks
    const int r_in = lane >> 3;              // 0..7 (== r&7, rows 8-aligned per call)
    const int lc   = (lane & 7) ^ r_in;      // logical chunk to fetch

    f32x4 acc[4][4];
    #pragma unroll
    for (int m = 0; m < 4; ++m)
        #pragma unroll
        for (int n = 0; n < 4; ++n)
            acc[m][n] = f32x4{0.f, 0.f, 0.f, 0.f};

    const long a_row0 = (long)bm * 128;
    const long b_row0 = (long)bn * 128;

    for (int kt = 0; kt < K / 64; ++kt) {
        __syncthreads();
        const int k0 = kt * 64 + lc * 8;
        #pragma unroll
        for (int c = 0; c < 4; ++c) {
            int cc = wave * 4 + c;
            int r  = cc * 8 + r_in;
            gld_lds16(A  + (a_row0 + r) * K + k0, &As[cc * 512]);
            gld_lds16(Bw + (b_row0 + r) * K + k0, &Bs[cc * 512]);
        }
        __syncthreads();

        bf16x8 af[4][2], bf[4][2];
        #pragma unroll
        for (int m = 0; m < 4; ++m)
            #pragma unroll
            for (int ks = 0; ks < 2; ++ks) {
                int r  = wm * 64 + m * 16 + l16;
                int pc = (ks * 4 + quad) ^ (r & 7);
                af[m][ks] = ld8(&As[r * 64 + pc * 8]);
            }
        #pragma unroll
        for (int n = 0; n < 4; ++n)
            #pragma unroll
            for (int ks = 0; ks < 2; ++ks) {
                int r  = wn * 64 + n * 16 + l16;
                int pc = (ks * 4 + quad) ^ (r & 7);
                bf[n][ks] = ld8(&Bs[r * 64 + pc * 8]);
            }
        #pragma unroll
        for (int ks = 0; ks < 2; ++ks)
            #pragma unroll
            for (int m = 0; m < 4; ++m)
                #pragma unroll
                for (int n = 0; n < 4; ++n)
                    acc[m][n] = __builtin_amdgcn_mfma_f32_16x16x32_bf16(
                        af[m][ks], bf[n][ks], acc[m][n], 0, 0, 0);
    }

    // epilogue: C/D layout col = lane&15, row = quad*4 + reg
    #pragma unroll
    for (int m = 0; m < 4; ++m) {
        int row = bm * 128 + wm * 64 + m * 16 + quad * 4;
        #pragma unroll
        for (int n = 0; n < 4; ++n) {
            int col = bn * 128 + wn * 64 + n * 16 + l16;
            if (MODE == 3) {
                float* O = (float*)out;
                #pragma unroll
                for (int r = 0; r < 4; ++r)
                    O[(long)(row + r) * 1024 + col] = acc[m][n][r];
            } else if (MODE == 2) {
                int h = col >> 6, hs = col & 63;
                int b = row >> 11, t = row & 2047;
                unsigned short* O = (unsigned short*)out;
                ushort4 pk;
                pk.x = f2bf(acc[m][n][0]); pk.y = f2bf(acc[m][n][1]);
                pk.z = f2bf(acc[m][n][2]); pk.w = f2bf(acc[m][n][3]);
                *(ushort4*)&O[(long)((b * 16 + h) * 64 + hs) * 2048 + t] = pk;
            } else {
                int h = col >> 6, hs = col & 63;
                int b = row >> 11;
                unsigned short* O = (unsigned short*)out;
                #pragma unroll
                for (int r = 0; r < 4; ++r) {
                    int t = (row + r) & 2047;
                    float v = acc[m][n][r];
                    if (MODE == 0) v *= 0.125f * 1.4426950408889634f;  // 1/sqrt(64) * log2e
                    O[(long)((b * 16 + h) * 2048 + t) * 64 + hs] = f2bf(v);
                }
            }
        }
    }
}

// ---------------- flash attention, logits already in log2 domain ---------------------
__global__ __launch_bounds__(256, 2) void attn(
    const unsigned short* __restrict__ Q,    // [B,NH,T,HS] bf16, pre-scaled by 0.125*log2e
    const unsigned short* __restrict__ Kb,   // [B,NH,T,HS] bf16
    const unsigned short* __restrict__ Vt,   // [B,NH,HS,T] bf16
    const float* __restrict__ bias_tab,      // [NH][4095], *log2e
    unsigned short* __restrict__ AO)         // [B,T,D] bf16
{
    __shared__ unsigned short Ks[64 * 64];
    __shared__ unsigned short Vs[64 * 64];
    __shared__ unsigned short Ps[128 * 72];  // stride 72: 16B-aligned rows, <=2-way banks

    const int tid  = threadIdx.x;
    const int wave = tid >> 6;
    const int lane = tid & 63;
    const int quad = lane >> 4;
    const int l16  = lane & 15;

    const int bh = blockIdx.y;          // b*16 + h
    const int b  = bh >> 4, h = bh & 15;
    const int q0 = blockIdx.x * 128;

    const unsigned short* Qg = Q  + (long)bh * T_SEQ * HSZ;
    const unsigned short* Kg = Kb + (long)bh * T_SEQ * HSZ;
    const unsigned short* Vg = Vt + (long)bh * HSZ * T_SEQ;
    const float* btab = bias_tab + h * 4095 + 2047;

    // Q fragments straight from global (contiguous 2KB region per wave)
    bf16x8 qf[2][2];
    #pragma unroll
    for (int m = 0; m < 2; ++m)
        #pragma unroll
        for (int ks = 0; ks < 2; ++ks) {
            int t = q0 + wave * 32 + m * 16 + l16;
            qf[m][ks] = ld8(&Qg[(long)t * 64 + ks * 32 + quad * 8]);
        }

    f32x4 o[2][4];
    float mi[2][4], li[2][4];
    #pragma unroll
    for (int m = 0; m < 2; ++m) {
        #pragma unroll
        for (int n = 0; n < 4; ++n) o[m][n] = f32x4{0.f, 0.f, 0.f, 0.f};
        #pragma unroll
        for (int r = 0; r < 4; ++r) { mi[m][r] = -__builtin_inff(); li[m][r] = 0.0f; }
    }

    const int r_in = lane >> 3;
    const int lc   = (lane & 7) ^ r_in;

    for (int kt = 0; kt < T_SEQ / 64; ++kt) {
        __syncthreads();
        #pragma unroll
        for (int c = 0; c < 2; ++c) {
            int cc = wave * 2 + c;
            int r  = cc * 8 + r_in;
            gld_lds16(Kg + (long)(kt * 64 + r) * 64 + lc * 8, &Ks[cc * 512]);
            gld_lds16(Vg + (long)r * T_SEQ + kt * 64 + lc * 8, &Vs[cc * 512]);
        }
        __syncthreads();

        // S = Q K^T  (col = token, row = query)
        bf16x8 kf[4][2];
        #pragma unroll
        for (int n = 0; n < 4; ++n)
            #pragma unroll
            for (int ks = 0; ks < 2; ++ks) {
                int r  = n * 16 + l16;
                int pc = (ks * 4 + quad) ^ (r & 7);
                kf[n][ks] = ld8(&Ks[r * 64 + pc * 8]);
            }
        f32x4 s[2][4];
        #pragma unroll
        for (int m = 0; m < 2; ++m)
            #pragma unroll
            for (int n = 0; n < 4; ++n) {
                f32x4 a = f32x4{0.f, 0.f, 0.f, 0.f};
                a = __builtin_amdgcn_mfma_f32_16x16x32_bf16(qf[m][0], kf[n][0], a, 0, 0, 0);
                a = __builtin_amdgcn_mfma_f32_16x16x32_bf16(qf[m][1], kf[n][1], a, 0, 0, 0);
                s[m][n] = a;
            }

        // bias + online softmax (everything in log2 domain)
        #pragma unroll
        for (int m = 0; m < 2; ++m) {
            int rowb = q0 + wave * 32 + m * 16 + quad * 4;
            #pragma unroll
            for (int n = 0; n < 4; ++n) {
                int col = kt * 64 + n * 16 + l16;
                #pragma unroll
                for (int r = 0; r < 4; ++r)
                    s[m][n][r] += btab[col - (rowb + r)];
            }
            float mx[4];
            #pragma unroll
            for (int r = 0; r < 4; ++r)
                mx[r] = fmaxf(fmaxf(s[m][0][r], s[m][1][r]), fmaxf(s[m][2][r], s[m][3][r]));
            #pragma unroll
            for (int st = 1; st < 16; st <<= 1)
                #pragma unroll
                for (int r = 0; r < 4; ++r)
                    mx[r] = fmaxf(mx[r], __shfl_xor(mx[r], st));
            float alpha[4], rs[4];
            #pragma unroll
            for (int r = 0; r < 4; ++r) {
                float mnew = fmaxf(mi[m][r], mx[r]);
                alpha[r] = __builtin_exp2f(mi[m][r] - mnew);
                mi[m][r] = mnew;
                rs[r] = 0.0f;
            }
            #pragma unroll
            for (int n = 0; n < 4; ++n)
                #pragma unroll
                for (int r = 0; r < 4; ++r) {
                    float p = __builtin_exp2f(s[m][n][r] - mi[m][r]);
                    s[m][n][r] = p;
                    rs[r] += p;
                }
            #pragma unroll
            for (int st = 1; st < 16; st <<= 1)
                #pragma unroll
                for (int r = 0; r < 4; ++r)
                    rs[r] += __shfl_xor(rs[r], st);
            #pragma unroll
            for (int r = 0; r < 4; ++r)
                li[m][r] = li[m][r] * alpha[r] + rs[r];
            #pragma unroll
            for (int n = 0; n < 4; ++n)
                #pragma unroll
                for (int r = 0; r < 4; ++r)
                    o[m][n][r] *= alpha[r];
            // P -> LDS (wave-private slab; C-layout -> A-layout transform)
            #pragma unroll
            for (int n = 0; n < 4; ++n)
                #pragma unroll
                for (int r = 0; r < 4; ++r)
                    Ps[(wave * 32 + m * 16 + quad * 4 + r) * 72 + n * 16 + l16] =
                        f2bf(s[m][n][r]);
        }

        asm volatile("s_waitcnt lgkmcnt(0)" ::: "memory");  // wave-private P write->read

        // O += P V
        bf16x8 vf[4][2], pf[2][2];
        #pragma unroll
        for (int n = 0; n < 4; ++n)
            #pragma unroll
            for (int ks = 0; ks < 2; ++ks) {
                int r  = n * 16 + l16;                     // hs
                int pc = (ks * 4 + quad) ^ (r & 7);
                vf[n][ks] = ld8(&Vs[r * 64 + pc * 8]);
            }
        #pragma unroll
        for (int m = 0; m < 2; ++m)
            #pragma unroll
            for (int ks = 0; ks < 2; ++ks)
                pf[m][ks] = ld8(&Ps[(wave * 32 + m * 16 + l16) * 72 + ks * 32 + quad * 8]);
        #pragma unroll
        for (int m = 0; m < 2; ++m)
            #pragma unroll
            for (int n = 0; n < 4; ++n) {
                o[m][n] = __builtin_amdgcn_mfma_f32_16x16x32_bf16(pf[m][0], vf[n][0], o[m][n], 0, 0, 0);
                o[m][n] = __builtin_amdgcn_mfma_f32_16x16x32_bf16(pf[m][1], vf[n][1], o[m][n], 0, 0, 0);
            }
    }

    // epilogue: normalize and write [B,T,D] bf16
    #pragma unroll
    for (int m = 0; m < 2; ++m) {
        int trow = q0 + wave * 32 + m * 16 + quad * 4;
        #pragma unroll
        for (int r = 0; r < 4; ++r) {
            float inv = 1.0f / li[m][r];
            #pragma unroll
            for (int n = 0; n < 4; ++n) {
                int col = h * 64 + n * 16 + l16;
                AO[(long)(b * T_SEQ + trow + r) * D_MODEL + col] = f2bf(o[m][n][r] * inv);
            }
        }
    }
}

// ---------------- launch ----------------
extern "C" void kernel_launch(void* const* d_in, const int* in_sizes, int n_in,
                              void* d_out, int out_size, void* d_ws, size_t ws_size,
                              hipStream_t stream) {
    const float* x   = (const float*)d_in[0];
    const float* wq  = (const float*)d_in[1];
    const float* wk  = (const float*)d_in[2];
    const float* wv  = (const float*)d_in[3];
    const float* wo  = (const float*)d_in[4];
    const float* rel = (const float*)d_in[5];

    char* ws = (char*)d_ws;
    unsigned short* Xbf = (unsigned short*)(ws);                      // 16 MiB (reused as AO)
    unsigned short* Wbf = (unsigned short*)(ws + (16l << 20));        // 8 MiB (Wq,Wk,Wv,Wo)
    unsigned short* Qb  = (unsigned short*)(ws + (24l << 20));        // 16 MiB
    unsigned short* Kbf = (unsigned short*)(ws + (40l << 20));        // 16 MiB
    unsigned short* Vtb = (unsigned short*)(ws + (56l << 20));        // 16 MiB
    float*          btb = (float*)(ws + (72l << 20));                 // 256 KiB

    cast_x<<<8192, 256, 0, stream>>>(x, Xbf, 2097152);
    cast_w<<<dim3(1024, 4), 256, 0, stream>>>(wq, wk, wv, wo, Wbf);
    bias_table<<<256, 256, 0, stream>>>(rel, btb);

    gemm_bt<0><<<dim3(8, 64), 256, 0, stream>>>(Xbf, Wbf + 0 * 1048576, Qb);
    gemm_bt<1><<<dim3(8, 64), 256, 0, stream>>>(Xbf, Wbf + 1 * 1048576, Kbf);
    gemm_bt<2><<<dim3(8, 64), 256, 0, stream>>>(Xbf, Wbf + 2 * 1048576, Vtb);

    unsigned short* AO = Xbf;  // X dead after the three projections
    attn<<<dim3(16, 64), 256, 0, stream>>>(Qb, Kbf, Vtb, btb, AO);

    gemm_bt<3><<<dim3(8, 64), 256, 0, stream>>>(AO, Wbf + 3 * 1048576, d_out);
}